// Round 3
// baseline (491.883 us; speedup 1.0000x reference)
//
#include <hip/hip_runtime.h>
#include <math.h>

#define B    64
#define CHI  20
#define DD   65536             // C*H*W = 64*32*32
#define CHUNKS 32
#define CHUNK  (DD / CHUNKS)   // 2048 floats = 8 KiB per frame per block

static_assert(DD % (4 * 256) == 0, "k_scores float4 tiling");
static_assert(CHUNK == 2048, "chunk geometry");
static_assert(256 * 21 * 4 < 65536, "k_apply LDS fits");

// ---------------------------------------------------------------------------
// Kernel 1: partial dot products  scores[b][c] = dot(frames[b][19], frames[b][c])
// grid = B*CHUNKS blocks, 256 threads. Each block: one (batch, chunk).
// Writes partials[b][chunk][c] (no atomics -> deterministic, no ws zero-init).
// ---------------------------------------------------------------------------
__global__ __launch_bounds__(256) void k_scores(const float* __restrict__ x,
                                                float* __restrict__ partials) {
    const int blk = blockIdx.x;
    const int b   = blk / CHUNKS;
    const int ch  = blk % CHUNKS;
    const int tid = threadIdx.x;

    const float4* xb = (const float4*)(x + (size_t)b * CHI * DD);
    const int cbase4 = ch * (CHUNK / 4);      // float4 index within a frame
    const int f4 = DD / 4;                    // float4 per frame

    // last frame (c = 19) chunk, kept in registers
    float4 l0 = xb[(size_t)19 * f4 + cbase4 + tid];
    float4 l1 = xb[(size_t)19 * f4 + cbase4 + tid + 256];

    float acc[CHI];
    #pragma unroll
    for (int c = 0; c < CHI; ++c) acc[c] = 0.0f;

    // c = 19 term directly from registers (saves one chunk re-read)
    acc[19] = l0.x*l0.x + l0.y*l0.y + l0.z*l0.z + l0.w*l0.w
            + l1.x*l1.x + l1.y*l1.y + l1.z*l1.z + l1.w*l1.w;

    #pragma unroll
    for (int c = 0; c < 19; ++c) {
        float4 v0 = xb[(size_t)c * f4 + cbase4 + tid];
        float4 v1 = xb[(size_t)c * f4 + cbase4 + tid + 256];
        acc[c] = l0.x*v0.x + l0.y*v0.y + l0.z*v0.z + l0.w*v0.w
               + l1.x*v1.x + l1.y*v1.y + l1.z*v1.z + l1.w*v1.w;
    }

    // per-wave shuffle reduction (wave = 64 lanes)
    #pragma unroll
    for (int c = 0; c < CHI; ++c) {
        float v = acc[c];
        #pragma unroll
        for (int off = 32; off > 0; off >>= 1) v += __shfl_down(v, off, 64);
        acc[c] = v;
    }

    __shared__ float lds[4][CHI];
    const int wave = tid >> 6, lane = tid & 63;
    if (lane == 0) {
        #pragma unroll
        for (int c = 0; c < CHI; ++c) lds[wave][c] = acc[c];
    }
    __syncthreads();
    if (tid < CHI) {
        float s = lds[0][tid] + lds[1][tid] + lds[2][tid] + lds[3][tid];
        partials[((size_t)b * CHUNKS + ch) * CHI + tid] = s;
    }
}

// ---------------------------------------------------------------------------
// Kernel 2: reduce partials over chunks, /chi, softmax over chi -> alpha[b][c]
// grid = B blocks x 64 threads (one wave).
// ---------------------------------------------------------------------------
__global__ __launch_bounds__(64) void k_softmax(const float* __restrict__ partials,
                                                float* __restrict__ alpha) {
    const int b = blockIdx.x;
    const int lane = threadIdx.x;

    float sv = 0.0f;
    float s = -INFINITY;
    if (lane < CHI) {
        #pragma unroll 4
        for (int k = 0; k < CHUNKS; ++k)
            sv += partials[((size_t)b * CHUNKS + k) * CHI + lane];
        sv /= (float)CHI;
        s = sv;
    }
    // wave-wide butterfly max
    float m = s;
    #pragma unroll
    for (int off = 1; off < 64; off <<= 1) m = fmaxf(m, __shfl_xor(m, off, 64));
    float e = (lane < CHI) ? expf(sv - m) : 0.0f;
    float sum = e;
    #pragma unroll
    for (int off = 1; off < 64; off <<= 1) sum += __shfl_xor(sum, off, 64);
    if (lane < CHI) alpha[(size_t)b * CHI + lane] = e / sum;
}

// ---------------------------------------------------------------------------
// Kernel 3: result[b][d] = sum_c x_flat[b][d*20+c] * alpha[b][c]
// Block stages a contiguous 20 KiB region (256 outputs x 20 floats) into LDS
// with dense float4 loads, then each thread reads its 20 floats via a
// stride-21 padded layout (21 odd -> 2-way bank aliasing = free).
// Batches processed in REVERSE order so the tail of phase 1's stream
// (still resident in the 256 MiB L3) is re-read first.
// grid = B*256 blocks x 256 threads.
// ---------------------------------------------------------------------------
__global__ __launch_bounds__(256) void k_apply(const float* __restrict__ x,
                                               const float* __restrict__ alpha,
                                               float* __restrict__ out) {
    const int b   = (B - 1) - (int)(blockIdx.x >> 8);   // reversed batch order
    const int blk = blockIdx.x & 255;
    const int t   = threadIdx.x;

    __shared__ float lds[256 * 21];   // element j -> lds[j + j/20] == [d_local*21 + c]

    const float4* src =
        (const float4*)(x + (size_t)b * CHI * DD + (size_t)blk * 256 * CHI);

    #pragma unroll
    for (int w = 0; w < 5; ++w) {
        const int f = w * 256 + t;      // float4 index within the 20 KiB region
        float4 v = src[f];
        const int j = 4 * f;            // j%20 in {0,4,8,12,16} -> no pad crossing
        const int p = j / 20;           // pad amount (= d_local)
        lds[j + p + 0] = v.x;
        lds[j + p + 1] = v.y;
        lds[j + p + 2] = v.z;
        lds[j + p + 3] = v.w;
    }

    // alpha for this batch (same 80 B for all threads -> L1 broadcast)
    const float* ab = alpha + (size_t)b * CHI;
    float a[CHI];
    #pragma unroll
    for (int k = 0; k < 5; ++k) {
        float4 v = ((const float4*)ab)[k];
        a[4*k+0] = v.x; a[4*k+1] = v.y; a[4*k+2] = v.z; a[4*k+3] = v.w;
    }

    __syncthreads();

    const int base = t * 21;
    float sum = 0.0f;
    #pragma unroll
    for (int c = 0; c < CHI; ++c) sum += lds[base + c] * a[c];

    out[(size_t)b * DD + (size_t)blk * 256 + t] = sum;
}

extern "C" void kernel_launch(void* const* d_in, const int* in_sizes, int n_in,
                              void* d_out, int out_size, void* d_ws, size_t ws_size,
                              hipStream_t stream) {
    const float* x = (const float*)d_in[0];
    float* out = (float*)d_out;

    float* partials = (float*)d_ws;                        // B*CHUNKS*CHI floats
    float* alpha    = partials + (size_t)B * CHUNKS * CHI; // B*CHI floats

    k_scores <<<B * CHUNKS, 256, 0, stream>>>(x, partials);
    k_softmax<<<B,          64,  0, stream>>>(partials, alpha);
    k_apply  <<<B * 256,    256, 0, stream>>>(x, alpha, out);
}